// Round 13
// baseline (166.352 us; speedup 1.0000x reference)
//
#include <hip/hip_runtime.h>

#define DH 128
#define SLOTS 64
#define BSH 13  // bucket shift: dst>>13 -> 8 ranges of 8192 nodes

typedef __bf16 bf16x8 __attribute__((ext_vector_type(8)));
typedef float f32x4 __attribute__((ext_vector_type(4)));
typedef float f32x2 __attribute__((ext_vector_type(2)));

__device__ __forceinline__ ushort f2b(float f) {
  union { float f; unsigned u; } c; c.f = f;
  unsigned u = c.u;
  unsigned r = (u + 0x7fffu + ((u >> 16) & 1u)) >> 16;
  return (ushort)r;
}
__device__ __forceinline__ unsigned char f2f8(float v) {
  return (unsigned char)(__builtin_amdgcn_cvt_pk_fp8_f32(v, v, 0, false) & 0xff);
}

// ---- fused: zero deg+gcnt | convert f32 -> bf16 + fp8 | weight pack ----
__global__ void k_prep(int4* __restrict__ degz, int nZero, int nz4,
                       const float* __restrict__ x, ushort* __restrict__ xb,
                       uint2* __restrict__ xf8, long n8, int nConv,
                       const float* __restrict__ Ws1, const float* __restrict__ Wn1,
                       const float* __restrict__ Ws2, const float* __restrict__ Wn2,
                       ushort* __restrict__ Wp1, ushort* __restrict__ Wp2) {
  int bid = blockIdx.x;
  if (bid < nZero) {
    int i = bid * 256 + threadIdx.x;
    if (i < nz4) degz[i] = int4{0, 0, 0, 0};
  } else if (bid < nZero + nConv) {
    long i = (long)(bid - nZero) * 256 + threadIdx.x;
    if (i >= n8) return;
    const float4* p = (const float4*)x + i * 2;
    float4 a = p[0], b = p[1];
    uint4 o;
    o.x = (unsigned)f2b(a.x) | ((unsigned)f2b(a.y) << 16);
    o.y = (unsigned)f2b(a.z) | ((unsigned)f2b(a.w) << 16);
    o.z = (unsigned)f2b(b.x) | ((unsigned)f2b(b.y) << 16);
    o.w = (unsigned)f2b(b.z) | ((unsigned)f2b(b.w) << 16);
    ((uint4*)xb)[i] = o;
    int w0 = __builtin_amdgcn_cvt_pk_fp8_f32(a.x, a.y, 0, false);
    w0 = __builtin_amdgcn_cvt_pk_fp8_f32(a.z, a.w, w0, true);
    int w1 = __builtin_amdgcn_cvt_pk_fp8_f32(b.x, b.y, 0, false);
    w1 = __builtin_amdgcn_cvt_pk_fp8_f32(b.z, b.w, w1, true);
    xf8[i] = uint2{(unsigned)w0, (unsigned)w1};
  } else {
    int idx = (bid - nZero - nConv) * 256 + threadIdx.x;
    if (idx >= 2 * 8 * 8 * 64 * 8) return;
    int layer = idx >> 15;
    int t = idx & 32767;
    int j = t & 7;
    int lane = (t >> 3) & 63;
    int cb = (t >> 9) & 7;
    int s = (t >> 12) & 7;
    int col = cb * 16 + (lane & 15);
    int k = s * 32 + ((lane >> 4) * 8) + j;
    const float* Wself = layer ? Ws2 : Ws1;
    const float* Wneigh = layer ? Wn2 : Wn1;
    float v = (k < 128) ? Wself[k * 128 + col] : Wneigh[(k - 128) * 128 + col];
    (layer ? Wp2 : Wp1)[t] = f2b(v);
  }
}

// ---- level 1: bucket edges by dst range (single pass, LDS-staged flush) ----
// Each round of 256 edges: LDS per-bucket count -> global base reservation ->
// ranked contiguous write. Flush chunks (~256B) are exclusively owned.
__global__ void k_bucket(const int* __restrict__ src, const int* __restrict__ dst,
                         uint2* __restrict__ ebuf, int* __restrict__ gcnt,
                         int E, int cap) {
  __shared__ int cnt[8], base[8], cur[8];
  int csz = (E + gridDim.x - 1) / gridDim.x;
  int beg = blockIdx.x * csz;
  int end = min(beg + csz, E);
  for (int r = beg; r < end; r += 256) {
    int i = r + threadIdx.x;
    int b = 0, d = 0, s = 0;
    if (threadIdx.x < 8) cnt[threadIdx.x] = 0;
    __syncthreads();
    bool live = i < end;
    if (live) {
      d = dst[i];
      s = src[i];
      b = d >> BSH;
      atomicAdd(&cnt[b], 1);
    }
    __syncthreads();
    if (threadIdx.x < 8) {
      base[threadIdx.x] = cnt[threadIdx.x] ? atomicAdd(&gcnt[threadIdx.x], cnt[threadIdx.x]) : 0;
      cur[threadIdx.x] = 0;
    }
    __syncthreads();
    if (live) {
      int rk = atomicAdd(&cur[b], 1);
      int pos = base[b] + rk;
      if (pos < cap) ebuf[(size_t)b * cap + pos] = uint2{(unsigned)s, (unsigned)d};
    }
    __syncthreads();
  }
}

// ---- level 2: padded-CSR fill from buckets; partition p stays on XCD p ----
__global__ void k_fillB(const uint2* __restrict__ ebuf, const int* __restrict__ gcnt,
                        int* __restrict__ deg, int* __restrict__ colsrc, int cap) {
  int p = blockIdx.x & 7;
  int chunk = blockIdx.x >> 3;  // 128 chunks per partition
  int cnt = min(gcnt[p], cap);
  int len = (cnt + 127) >> 7;
  int beg = chunk * len;
  int end = min(beg + len, cnt);
  const uint2* eb = ebuf + (size_t)p * cap;
  for (int i = beg + threadIdx.x; i < end; i += 256) {
    uint2 e = eb[i];
    int d = (int)e.y;
    int r = atomicAdd(&deg[d], 1);
    if (r < SLOTS) colsrc[(size_t)d * SLOTS + r] = (int)e.x;
  }
}

// decode 8 fp8 (e4m3) from uint2 and accumulate
__device__ __forceinline__ void acc8f8(float* a, uint2 v) {
  f32x2 p0 = __builtin_amdgcn_cvt_pk_f32_fp8(v.x, false);
  f32x2 p1 = __builtin_amdgcn_cvt_pk_f32_fp8(v.x, true);
  f32x2 p2 = __builtin_amdgcn_cvt_pk_f32_fp8(v.y, false);
  f32x2 p3 = __builtin_amdgcn_cvt_pk_f32_fp8(v.y, true);
  a[0] += p0.x; a[1] += p0.y; a[2] += p1.x; a[3] += p1.y;
  a[4] += p2.x; a[5] += p2.y; a[6] += p3.x; a[7] += p3.y;
}

// ---- fused aggregate + GEMM, 1024 threads / 64 nodes per block ----
// Phase 1: 64 groups x 16 lanes, one node per group; fp8 row gathers (128B,
//          uint2/lane), x8 unrolled; padded-CSR edge list (node*SLOTS, deg);
//          f32 accumulate, mean -> bf16 -> LDS hn[64][136].
// Phase 2: 16 waves; wave w: row-group w>>2, col-blocks (w&3)*2,+1; bf16 MFMA.
template <int RELU, int OUTF32, int WRITEF8>
__global__ __launch_bounds__(1024, 8) void k_aggemm(
    const ushort* __restrict__ feat, const uint2* __restrict__ feat8,
    const int* __restrict__ deg, const int* __restrict__ colsrc,
    const ushort* __restrict__ Wp, const float* __restrict__ bias,
    void* __restrict__ outp, unsigned char* __restrict__ outf8, int M) {
  __shared__ ushort hn[64][136];
  int tid = threadIdx.x;

  // ---- phase 1: aggregation (fp8 gathers over padded CSR) ----
  {
    int g = tid >> 4, l = tid & 15;
    int node = blockIdx.x * 64 + g;
    float a[8] = {0.f, 0.f, 0.f, 0.f, 0.f, 0.f, 0.f, 0.f};
    float sc = 0.f;
    if (node < M) {
      int dd = min(deg[node], SLOTS);
      const int* cs = colsrc + (size_t)node * SLOTS;
      int e = 0;
      for (; e + 8 <= dd; e += 8) {
        int s0 = cs[e], s1 = cs[e + 1], s2 = cs[e + 2], s3 = cs[e + 3];
        int s4 = cs[e + 4], s5 = cs[e + 5], s6 = cs[e + 6], s7 = cs[e + 7];
        uint2 v0 = feat8[(size_t)s0 * 16 + l];
        uint2 v1 = feat8[(size_t)s1 * 16 + l];
        uint2 v2 = feat8[(size_t)s2 * 16 + l];
        uint2 v3 = feat8[(size_t)s3 * 16 + l];
        uint2 v4 = feat8[(size_t)s4 * 16 + l];
        uint2 v5 = feat8[(size_t)s5 * 16 + l];
        uint2 v6 = feat8[(size_t)s6 * 16 + l];
        uint2 v7 = feat8[(size_t)s7 * 16 + l];
        acc8f8(a, v0); acc8f8(a, v1); acc8f8(a, v2); acc8f8(a, v3);
        acc8f8(a, v4); acc8f8(a, v5); acc8f8(a, v6); acc8f8(a, v7);
      }
      for (; e + 4 <= dd; e += 4) {
        int s0 = cs[e], s1 = cs[e + 1], s2 = cs[e + 2], s3 = cs[e + 3];
        uint2 v0 = feat8[(size_t)s0 * 16 + l];
        uint2 v1 = feat8[(size_t)s1 * 16 + l];
        uint2 v2 = feat8[(size_t)s2 * 16 + l];
        uint2 v3 = feat8[(size_t)s3 * 16 + l];
        acc8f8(a, v0); acc8f8(a, v1); acc8f8(a, v2); acc8f8(a, v3);
      }
      for (; e < dd; ++e) acc8f8(a, feat8[(size_t)cs[e] * 16 + l]);
      sc = 1.0f / fmaxf((float)dd, 1.0f);
    }
    uint4 o;
    o.x = (unsigned)f2b(a[0] * sc) | ((unsigned)f2b(a[1] * sc) << 16);
    o.y = (unsigned)f2b(a[2] * sc) | ((unsigned)f2b(a[3] * sc) << 16);
    o.z = (unsigned)f2b(a[4] * sc) | ((unsigned)f2b(a[5] * sc) << 16);
    o.w = (unsigned)f2b(a[6] * sc) | ((unsigned)f2b(a[7] * sc) << 16);
    *(uint4*)&hn[g][l * 8] = o;
  }
  __syncthreads();

  // ---- phase 2: GEMM ----
  int wave = tid >> 6, lane = tid & 63;
  int rg = wave >> 2;
  int cb0 = (wave & 3) * 2;
  int rowA = blockIdx.x * 64 + rg * 16 + (lane & 15);
  int kq = lane >> 4;
  bool valid = rowA < M;
  size_t abase = (size_t)rowA * DH + kq * 8;
  int lrow = rg * 16 + (lane & 15);
  f32x4 acc0 = {}, acc1 = {};
#pragma unroll
  for (int hf = 0; hf < 2; ++hf) {
#pragma unroll
    for (int ks = 0; ks < 4; ++ks) {
      bf16x8 a = {};
      if (hf == 0) {
        if (valid) a = __builtin_bit_cast(bf16x8, *(const uint4*)(feat + abase + ks * 32));
      } else {
        a = __builtin_bit_cast(bf16x8, *(const uint4*)&hn[lrow][ks * 32 + kq * 8]);
      }
      int sg = hf * 4 + ks;
      const ushort* wp = Wp + sg * 4096 + lane * 8;
      bf16x8 b0 = __builtin_bit_cast(bf16x8, *(const uint4*)(wp + cb0 * 512));
      bf16x8 b1 = __builtin_bit_cast(bf16x8, *(const uint4*)(wp + (cb0 + 1) * 512));
      acc0 = __builtin_amdgcn_mfma_f32_16x16x32_bf16(a, b0, acc0, 0, 0, 0);
      acc1 = __builtin_amdgcn_mfma_f32_16x16x32_bf16(a, b1, acc1, 0, 0, 0);
    }
  }
  // C/D layout: col = lane&15, row = (lane>>4)*4 + reg
  int col = lane & 15;
  int row0 = blockIdx.x * 64 + rg * 16 + (lane >> 4) * 4;
#pragma unroll
  for (int t = 0; t < 2; ++t) {
    int cb = cb0 + t;
    float bv = bias[cb * 16 + col];
    f32x4 acc = t ? acc1 : acc0;
#pragma unroll
    for (int j = 0; j < 4; ++j) {
      int rr = row0 + j;
      if (rr < M) {
        float v = acc[j] + bv;
        if (RELU) v = fmaxf(v, 0.f);
        if (OUTF32)
          ((float*)outp)[(size_t)rr * DH + cb * 16 + col] = v;
        else
          ((ushort*)outp)[(size_t)rr * DH + cb * 16 + col] = f2b(v);
        if (WRITEF8)
          outf8[(size_t)rr * DH + cb * 16 + col] = f2f8(v);
      }
    }
  }
}

extern "C" void kernel_launch(void* const* d_in, const int* in_sizes, int n_in,
                              void* d_out, int out_size, void* d_ws, size_t ws_size,
                              hipStream_t stream) {
  const float* x = (const float*)d_in[0];
  const int* src = (const int*)d_in[1];
  const int* dst = (const int*)d_in[2];
  const float* Wself1 = (const float*)d_in[3];
  const float* Wneigh1 = (const float*)d_in[4];
  const float* b1 = (const float*)d_in[5];
  const float* Wself2 = (const float*)d_in[6];
  const float* Wneigh2 = (const float*)d_in[7];
  const float* b2 = (const float*)d_in[8];
  int N = in_sizes[0] / DH;
  int E = in_sizes[1];

  char* w = (char*)d_ws;
  auto alloc = [&](size_t bytes) {
    char* p = w;
    w += (bytes + 255) & ~(size_t)255;
    return p;
  };
  ushort* xb = (ushort*)alloc((size_t)N * DH * 2);
  ushort* hb = (ushort*)alloc((size_t)N * DH * 2);
  unsigned char* xf8 = (unsigned char*)alloc((size_t)N * DH);
  unsigned char* hf8 = (unsigned char*)alloc((size_t)N * DH);
  ushort* Wp1 = (ushort*)alloc(32768 * 2);
  ushort* Wp2 = (ushort*)alloc(32768 * 2);
  int* deg = (int*)alloc(((size_t)N + 8) * 4);  // deg[N] then gcnt[8]
  int* gcnt = deg + N;
  int* colsrc = (int*)alloc((size_t)N * SLOTS * 4);
  int cap = E / 8 + 65536;
  uint2* ebuf = (uint2*)alloc((size_t)8 * cap * 8);

  // fused prep: zero deg+gcnt | convert+fp8 | pack
  int nz4 = (N + 8 + 3) / 4;
  int nZero = (nz4 + 255) / 256;
  long n8 = (long)N * DH / 8;
  int nConv = (int)((n8 + 255) / 256);
  int nPack = (2 * 8 * 8 * 64 * 8 + 255) / 256;
  k_prep<<<nZero + nConv + nPack, 256, 0, stream>>>(
      (int4*)deg, nZero, nz4, x, xb, (uint2*)xf8, n8, nConv,
      Wself1, Wneigh1, Wself2, Wneigh2, Wp1, Wp2);

  // two-level fill: bucket by dst range, then XCD-local padded-CSR scatter
  k_bucket<<<256, 256, 0, stream>>>(src, dst, ebuf, gcnt, E, cap);
  k_fillB<<<128 * 8, 256, 0, stream>>>(ebuf, gcnt, deg, colsrc, cap);

  int gb = (N + 63) / 64;
  k_aggemm<1, 0, 1><<<gb, 1024, 0, stream>>>(xb, (const uint2*)xf8, deg, colsrc,
                                             Wp1, b1, hb, hf8, N);
  k_aggemm<0, 1, 0><<<gb, 1024, 0, stream>>>(hb, (const uint2*)hf8, deg, colsrc,
                                             Wp2, b2, d_out, nullptr, N);
}

// Round 14
// 152.011 us; speedup vs baseline: 1.0943x; 1.0943x over previous
//
#include <hip/hip_runtime.h>

#define DH 128
#define SLOTS 64

typedef __bf16 bf16x8 __attribute__((ext_vector_type(8)));
typedef float f32x4 __attribute__((ext_vector_type(4)));
typedef float f32x2 __attribute__((ext_vector_type(2)));

__device__ __forceinline__ ushort f2b(float f) {
  union { float f; unsigned u; } c; c.f = f;
  unsigned u = c.u;
  unsigned r = (u + 0x7fffu + ((u >> 16) & 1u)) >> 16;
  return (ushort)r;
}
__device__ __forceinline__ unsigned char f2f8(float v) {
  return (unsigned char)(__builtin_amdgcn_cvt_pk_fp8_f32(v, v, 0, false) & 0xff);
}

// ---- fused: zero deg | convert f32 -> bf16 + fp8 | weight pack ----
__global__ void k_prep(int4* __restrict__ degz, int nZero, int nz4,
                       const float* __restrict__ x, ushort* __restrict__ xb,
                       uint2* __restrict__ xf8, long n8, int nConv,
                       const float* __restrict__ Ws1, const float* __restrict__ Wn1,
                       const float* __restrict__ Ws2, const float* __restrict__ Wn2,
                       ushort* __restrict__ Wp1, ushort* __restrict__ Wp2) {
  int bid = blockIdx.x;
  if (bid < nZero) {
    int i = bid * 256 + threadIdx.x;
    if (i < nz4) degz[i] = int4{0, 0, 0, 0};
  } else if (bid < nZero + nConv) {
    long i = (long)(bid - nZero) * 256 + threadIdx.x;
    if (i >= n8) return;
    const float4* p = (const float4*)x + i * 2;
    float4 a = p[0], b = p[1];
    uint4 o;
    o.x = (unsigned)f2b(a.x) | ((unsigned)f2b(a.y) << 16);
    o.y = (unsigned)f2b(a.z) | ((unsigned)f2b(a.w) << 16);
    o.z = (unsigned)f2b(b.x) | ((unsigned)f2b(b.y) << 16);
    o.w = (unsigned)f2b(b.z) | ((unsigned)f2b(b.w) << 16);
    ((uint4*)xb)[i] = o;
    int w0 = __builtin_amdgcn_cvt_pk_fp8_f32(a.x, a.y, 0, false);
    w0 = __builtin_amdgcn_cvt_pk_fp8_f32(a.z, a.w, w0, true);
    int w1 = __builtin_amdgcn_cvt_pk_fp8_f32(b.x, b.y, 0, false);
    w1 = __builtin_amdgcn_cvt_pk_fp8_f32(b.z, b.w, w1, true);
    xf8[i] = uint2{(unsigned)w0, (unsigned)w1};
  } else {
    int idx = (bid - nZero - nConv) * 256 + threadIdx.x;
    if (idx >= 2 * 8 * 8 * 64 * 8) return;
    int layer = idx >> 15;
    int t = idx & 32767;
    int j = t & 7;
    int lane = (t >> 3) & 63;
    int cb = (t >> 9) & 7;
    int s = (t >> 12) & 7;
    int col = cb * 16 + (lane & 15);
    int k = s * 32 + ((lane >> 4) * 8) + j;
    const float* Wself = layer ? Ws2 : Ws1;
    const float* Wneigh = layer ? Wn2 : Wn1;
    float v = (k < 128) ? Wself[k * 128 + col] : Wneigh[(k - 128) * 128 + col];
    (layer ? Wp2 : Wp1)[t] = f2b(v);
  }
}

// ---- padded-CSR fill, XCD-partitioned by dst range (R12, proven) ----
__global__ void k_fill8p(const int* __restrict__ src, const int* __restrict__ dst,
                         int* __restrict__ deg, int* __restrict__ colsrc,
                         int E, int nper, int chunkSz) {
  int part = blockIdx.x & 7;
  int chunk = blockIdx.x >> 3;
  int lo = part * nper, hi = lo + nper;
  int base = chunk * chunkSz;
  int end = min(base + chunkSz, E);
  for (int i = base + threadIdx.x; i < end; i += 256) {
    int d = dst[i];
    int s = src[i];
    if (d >= lo && d < hi) {
      int r = atomicAdd(&deg[d], 1);
      if (r < SLOTS) colsrc[(size_t)d * SLOTS + r] = s;
    }
  }
}

// decode 16 fp8 (e4m3) from uint4 and accumulate
__device__ __forceinline__ void acc16f8(float* a, uint4 v) {
  f32x2 p0 = __builtin_amdgcn_cvt_pk_f32_fp8(v.x, false);
  f32x2 p1 = __builtin_amdgcn_cvt_pk_f32_fp8(v.x, true);
  f32x2 p2 = __builtin_amdgcn_cvt_pk_f32_fp8(v.y, false);
  f32x2 p3 = __builtin_amdgcn_cvt_pk_f32_fp8(v.y, true);
  f32x2 p4 = __builtin_amdgcn_cvt_pk_f32_fp8(v.z, false);
  f32x2 p5 = __builtin_amdgcn_cvt_pk_f32_fp8(v.z, true);
  f32x2 p6 = __builtin_amdgcn_cvt_pk_f32_fp8(v.w, false);
  f32x2 p7 = __builtin_amdgcn_cvt_pk_f32_fp8(v.w, true);
  a[0] += p0.x;  a[1] += p0.y;  a[2] += p1.x;  a[3] += p1.y;
  a[4] += p2.x;  a[5] += p2.y;  a[6] += p3.x;  a[7] += p3.y;
  a[8] += p4.x;  a[9] += p4.y;  a[10] += p5.x; a[11] += p5.y;
  a[12] += p6.x; a[13] += p6.y; a[14] += p7.x; a[15] += p7.y;
}

// ---- fused aggregate + GEMM, 512 threads / 64 nodes per block ----
// Phase 1: 64 groups x 8 lanes, one node per group; each lane loads 16B uint4
//          => one vmem instr covers 8 FULL fp8 rows (2x fewer gather instrs
//          than the 16-lane layout). x4 unrolled, f32 accum (16 feats/lane),
//          mean -> bf16 -> LDS hn[64][136].
// Phase 2: 8 waves; wave w: row-group w>>1 (16 rows), col-blocks (w&1)*4..+3.
//          256 MFMAs/block total (same as before).
template <int RELU, int OUTF32, int WRITEF8>
__global__ __launch_bounds__(512, 8) void k_aggemm(
    const ushort* __restrict__ feat, const uint4* __restrict__ feat8,
    const int* __restrict__ deg, const int* __restrict__ colsrc,
    const ushort* __restrict__ Wp, const float* __restrict__ bias,
    void* __restrict__ outp, unsigned char* __restrict__ outf8, int M) {
  __shared__ ushort hn[64][136];
  int tid = threadIdx.x;

  // ---- phase 1: aggregation (full-row fp8 gathers, 8 lanes/node) ----
  {
    int g = tid >> 3, l = tid & 7;
    int node = blockIdx.x * 64 + g;
    float a[16];
#pragma unroll
    for (int q = 0; q < 16; ++q) a[q] = 0.f;
    float sc = 0.f;
    if (node < M) {
      int dd = min(deg[node], SLOTS);
      const int* cs = colsrc + (size_t)node * SLOTS;
      int e = 0;
      for (; e + 4 <= dd; e += 4) {
        int s0 = cs[e], s1 = cs[e + 1], s2 = cs[e + 2], s3 = cs[e + 3];
        uint4 v0 = feat8[(size_t)s0 * 8 + l];
        uint4 v1 = feat8[(size_t)s1 * 8 + l];
        uint4 v2 = feat8[(size_t)s2 * 8 + l];
        uint4 v3 = feat8[(size_t)s3 * 8 + l];
        acc16f8(a, v0); acc16f8(a, v1); acc16f8(a, v2); acc16f8(a, v3);
      }
      for (; e < dd; ++e) acc16f8(a, feat8[(size_t)cs[e] * 8 + l]);
      sc = 1.0f / fmaxf((float)dd, 1.0f);
    }
    uint4 o0, o1;
    o0.x = (unsigned)f2b(a[0] * sc) | ((unsigned)f2b(a[1] * sc) << 16);
    o0.y = (unsigned)f2b(a[2] * sc) | ((unsigned)f2b(a[3] * sc) << 16);
    o0.z = (unsigned)f2b(a[4] * sc) | ((unsigned)f2b(a[5] * sc) << 16);
    o0.w = (unsigned)f2b(a[6] * sc) | ((unsigned)f2b(a[7] * sc) << 16);
    o1.x = (unsigned)f2b(a[8] * sc) | ((unsigned)f2b(a[9] * sc) << 16);
    o1.y = (unsigned)f2b(a[10] * sc) | ((unsigned)f2b(a[11] * sc) << 16);
    o1.z = (unsigned)f2b(a[12] * sc) | ((unsigned)f2b(a[13] * sc) << 16);
    o1.w = (unsigned)f2b(a[14] * sc) | ((unsigned)f2b(a[15] * sc) << 16);
    *(uint4*)&hn[g][l * 16] = o0;
    *(uint4*)&hn[g][l * 16 + 8] = o1;
  }
  __syncthreads();

  // ---- phase 2: GEMM (8 waves: 4 row-groups x 2 col-halves) ----
  int wave = tid >> 6, lane = tid & 63;
  int rg = wave >> 1;           // row-group 0..3 (16 rows each)
  int cb0 = (wave & 1) * 4;     // col-blocks cb0..cb0+3
  int rowA = blockIdx.x * 64 + rg * 16 + (lane & 15);
  int kq = lane >> 4;
  bool valid = rowA < M;
  size_t abase = (size_t)rowA * DH + kq * 8;
  int lrow = rg * 16 + (lane & 15);
  f32x4 acc[4] = {};
#pragma unroll
  for (int hf = 0; hf < 2; ++hf) {
#pragma unroll
    for (int ks = 0; ks < 4; ++ks) {
      bf16x8 a = {};
      if (hf == 0) {
        if (valid) a = __builtin_bit_cast(bf16x8, *(const uint4*)(feat + abase + ks * 32));
      } else {
        a = __builtin_bit_cast(bf16x8, *(const uint4*)&hn[lrow][ks * 32 + kq * 8]);
      }
      int sg = hf * 4 + ks;
      const ushort* wp = Wp + sg * 4096 + lane * 8;
#pragma unroll
      for (int t = 0; t < 4; ++t) {
        bf16x8 b = __builtin_bit_cast(bf16x8, *(const uint4*)(wp + (cb0 + t) * 512));
        acc[t] = __builtin_amdgcn_mfma_f32_16x16x32_bf16(a, b, acc[t], 0, 0, 0);
      }
    }
  }
  // C/D layout: col = lane&15, row = (lane>>4)*4 + reg
  int col = lane & 15;
  int row0 = blockIdx.x * 64 + rg * 16 + (lane >> 4) * 4;
#pragma unroll
  for (int t = 0; t < 4; ++t) {
    int cb = cb0 + t;
    float bv = bias[cb * 16 + col];
#pragma unroll
    for (int j = 0; j < 4; ++j) {
      int rr = row0 + j;
      if (rr < M) {
        float v = acc[t][j] + bv;
        if (RELU) v = fmaxf(v, 0.f);
        if (OUTF32)
          ((float*)outp)[(size_t)rr * DH + cb * 16 + col] = v;
        else
          ((ushort*)outp)[(size_t)rr * DH + cb * 16 + col] = f2b(v);
        if (WRITEF8)
          outf8[(size_t)rr * DH + cb * 16 + col] = f2f8(v);
      }
    }
  }
}

extern "C" void kernel_launch(void* const* d_in, const int* in_sizes, int n_in,
                              void* d_out, int out_size, void* d_ws, size_t ws_size,
                              hipStream_t stream) {
  const float* x = (const float*)d_in[0];
  const int* src = (const int*)d_in[1];
  const int* dst = (const int*)d_in[2];
  const float* Wself1 = (const float*)d_in[3];
  const float* Wneigh1 = (const float*)d_in[4];
  const float* b1 = (const float*)d_in[5];
  const float* Wself2 = (const float*)d_in[6];
  const float* Wneigh2 = (const float*)d_in[7];
  const float* b2 = (const float*)d_in[8];
  int N = in_sizes[0] / DH;
  int E = in_sizes[1];

  char* w = (char*)d_ws;
  auto alloc = [&](size_t bytes) {
    char* p = w;
    w += (bytes + 255) & ~(size_t)255;
    return p;
  };
  ushort* xb = (ushort*)alloc((size_t)N * DH * 2);
  ushort* hb = (ushort*)alloc((size_t)N * DH * 2);
  unsigned char* xf8 = (unsigned char*)alloc((size_t)N * DH);
  unsigned char* hf8 = (unsigned char*)alloc((size_t)N * DH);
  ushort* Wp1 = (ushort*)alloc(32768 * 2);
  ushort* Wp2 = (ushort*)alloc(32768 * 2);
  int* deg = (int*)alloc((size_t)N * 4);
  int* colsrc = (int*)alloc((size_t)N * SLOTS * 4);

  // fused prep: zero deg | convert+fp8 | pack
  int nz4 = (N + 3) / 4;
  int nZero = (nz4 + 255) / 256;
  long n8 = (long)N * DH / 8;
  int nConv = (int)((n8 + 255) / 256);
  int nPack = (2 * 8 * 8 * 64 * 8 + 255) / 256;
  k_prep<<<nZero + nConv + nPack, 256, 0, stream>>>(
      (int4*)deg, nZero, nz4, x, xb, (uint2*)xf8, n8, nConv,
      Wself1, Wneigh1, Wself2, Wneigh2, Wp1, Wp2);

  // padded-CSR fill (R12, proven)
  int nper = (N + 7) / 8;
  int nchunk = 256;
  int chunkSz = (E + nchunk - 1) / nchunk;
  k_fill8p<<<nchunk * 8, 256, 0, stream>>>(src, dst, deg, colsrc, E, nper, chunkSz);

  int gb = (N + 63) / 64;
  k_aggemm<1, 0, 1><<<gb, 512, 0, stream>>>(xb, (const uint4*)xf8, deg, colsrc,
                                            Wp1, b1, hb, hf8, N);
  k_aggemm<0, 1, 0><<<gb, 512, 0, stream>>>(hb, (const uint4*)hf8, deg, colsrc,
                                            Wp2, b2, d_out, nullptr, N);
}

// Round 15
// 130.632 us; speedup vs baseline: 1.2734x; 1.1637x over previous
//
#include <hip/hip_runtime.h>

#define DH 128
#define SLOTS 64

typedef __bf16 bf16x8 __attribute__((ext_vector_type(8)));
typedef float f32x4 __attribute__((ext_vector_type(4)));
typedef float f32x2 __attribute__((ext_vector_type(2)));

__device__ __forceinline__ ushort f2b(float f) {
  union { float f; unsigned u; } c; c.f = f;
  unsigned u = c.u;
  unsigned r = (u + 0x7fffu + ((u >> 16) & 1u)) >> 16;
  return (ushort)r;
}
__device__ __forceinline__ unsigned char f2f8(float v) {
  return (unsigned char)(__builtin_amdgcn_cvt_pk_fp8_f32(v, v, 0, false) & 0xff);
}

// ---- fused: zero deg | convert f32 -> bf16 + fp8 | weight pack ----
__global__ void k_prep(int4* __restrict__ degz, int nZero, int nz4,
                       const float* __restrict__ x, ushort* __restrict__ xb,
                       uint2* __restrict__ xf8, long n8, int nConv,
                       const float* __restrict__ Ws1, const float* __restrict__ Wn1,
                       const float* __restrict__ Ws2, const float* __restrict__ Wn2,
                       ushort* __restrict__ Wp1, ushort* __restrict__ Wp2) {
  int bid = blockIdx.x;
  if (bid < nZero) {
    int i = bid * 256 + threadIdx.x;
    if (i < nz4) degz[i] = int4{0, 0, 0, 0};
  } else if (bid < nZero + nConv) {
    long i = (long)(bid - nZero) * 256 + threadIdx.x;
    if (i >= n8) return;
    const float4* p = (const float4*)x + i * 2;
    float4 a = p[0], b = p[1];
    uint4 o;
    o.x = (unsigned)f2b(a.x) | ((unsigned)f2b(a.y) << 16);
    o.y = (unsigned)f2b(a.z) | ((unsigned)f2b(a.w) << 16);
    o.z = (unsigned)f2b(b.x) | ((unsigned)f2b(b.y) << 16);
    o.w = (unsigned)f2b(b.z) | ((unsigned)f2b(b.w) << 16);
    ((uint4*)xb)[i] = o;
    int w0 = __builtin_amdgcn_cvt_pk_fp8_f32(a.x, a.y, 0, false);
    w0 = __builtin_amdgcn_cvt_pk_fp8_f32(a.z, a.w, w0, true);
    int w1 = __builtin_amdgcn_cvt_pk_fp8_f32(b.x, b.y, 0, false);
    w1 = __builtin_amdgcn_cvt_pk_fp8_f32(b.z, b.w, w1, true);
    xf8[i] = uint2{(unsigned)w0, (unsigned)w1};
  } else {
    int idx = (bid - nZero - nConv) * 256 + threadIdx.x;
    if (idx >= 2 * 8 * 8 * 64 * 8) return;
    int layer = idx >> 15;
    int t = idx & 32767;
    int j = t & 7;
    int lane = (t >> 3) & 63;
    int cb = (t >> 9) & 7;
    int s = (t >> 12) & 7;
    int col = cb * 16 + (lane & 15);
    int k = s * 32 + ((lane >> 4) * 8) + j;
    const float* Wself = layer ? Ws2 : Ws1;
    const float* Wneigh = layer ? Wn2 : Wn1;
    float v = (k < 128) ? Wself[k * 128 + col] : Wneigh[(k - 128) * 128 + col];
    (layer ? Wp2 : Wp1)[t] = f2b(v);
  }
}

// ---- padded-CSR fill, XCD-partitioned by dst range ----
// int4-vectorized dst scan (4 edges/load); src loaded only for in-range edges
// (1/8 of them) -> ~6x fewer scan instructions than the scalar version.
__global__ void k_fill8p(const int* __restrict__ src, const int* __restrict__ dst,
                         int* __restrict__ deg, int* __restrict__ colsrc,
                         int E, int nper, int chunkSz) {
  int part = blockIdx.x & 7;
  int chunk = blockIdx.x >> 3;
  int lo = part * nper, hi = lo + nper;
  int base = chunk * chunkSz;  // chunkSz % 4 == 0
  int end = min(base + chunkSz, E);
  int i = base + threadIdx.x * 4;
  for (; i + 4 <= end; i += 1024) {
    int4 d4 = *(const int4*)(dst + i);
    int dd[4] = {d4.x, d4.y, d4.z, d4.w};
#pragma unroll
    for (int k = 0; k < 4; ++k) {
      int d = dd[k];
      if (d >= lo && d < hi) {
        int s = src[i + k];
        int r = atomicAdd(&deg[d], 1);
        if (r < SLOTS) colsrc[(size_t)d * SLOTS + r] = s;
      }
    }
  }
  // scalar tail (E not multiple of 4)
  for (; i < end; ++i) {
    int d = dst[i];
    if (d >= lo && d < hi) {
      int s = src[i];
      int r = atomicAdd(&deg[d], 1);
      if (r < SLOTS) colsrc[(size_t)d * SLOTS + r] = s;
    }
  }
}

// decode 8 fp8 (e4m3) from uint2 and accumulate
__device__ __forceinline__ void acc8f8(float* a, uint2 v) {
  f32x2 p0 = __builtin_amdgcn_cvt_pk_f32_fp8(v.x, false);
  f32x2 p1 = __builtin_amdgcn_cvt_pk_f32_fp8(v.x, true);
  f32x2 p2 = __builtin_amdgcn_cvt_pk_f32_fp8(v.y, false);
  f32x2 p3 = __builtin_amdgcn_cvt_pk_f32_fp8(v.y, true);
  a[0] += p0.x; a[1] += p0.y; a[2] += p1.x; a[3] += p1.y;
  a[4] += p2.x; a[5] += p2.y; a[6] += p3.x; a[7] += p3.y;
}

// ---- fused aggregate + GEMM, 1024 threads / 64 nodes per block (R12 exact) ----
// Phase 1: 64 groups x 16 lanes, one node per group; fp8 row gathers (128B,
//          uint2/lane), x8 unrolled; padded-CSR edge list (node*SLOTS, deg);
//          f32 accumulate, mean -> bf16 -> LDS hn[64][136].
// Phase 2: 16 waves; wave w: row-group w>>2, col-blocks (w&3)*2,+1; bf16 MFMA.
template <int RELU, int OUTF32, int WRITEF8>
__global__ __launch_bounds__(1024, 8) void k_aggemm(
    const ushort* __restrict__ feat, const uint2* __restrict__ feat8,
    const int* __restrict__ deg, const int* __restrict__ colsrc,
    const ushort* __restrict__ Wp, const float* __restrict__ bias,
    void* __restrict__ outp, unsigned char* __restrict__ outf8, int M) {
  __shared__ ushort hn[64][136];
  int tid = threadIdx.x;

  // ---- phase 1: aggregation (fp8 gathers over padded CSR) ----
  {
    int g = tid >> 4, l = tid & 15;
    int node = blockIdx.x * 64 + g;
    float a[8] = {0.f, 0.f, 0.f, 0.f, 0.f, 0.f, 0.f, 0.f};
    float sc = 0.f;
    if (node < M) {
      int dd = min(deg[node], SLOTS);
      const int* cs = colsrc + (size_t)node * SLOTS;
      int e = 0;
      for (; e + 8 <= dd; e += 8) {
        int s0 = cs[e], s1 = cs[e + 1], s2 = cs[e + 2], s3 = cs[e + 3];
        int s4 = cs[e + 4], s5 = cs[e + 5], s6 = cs[e + 6], s7 = cs[e + 7];
        uint2 v0 = feat8[(size_t)s0 * 16 + l];
        uint2 v1 = feat8[(size_t)s1 * 16 + l];
        uint2 v2 = feat8[(size_t)s2 * 16 + l];
        uint2 v3 = feat8[(size_t)s3 * 16 + l];
        uint2 v4 = feat8[(size_t)s4 * 16 + l];
        uint2 v5 = feat8[(size_t)s5 * 16 + l];
        uint2 v6 = feat8[(size_t)s6 * 16 + l];
        uint2 v7 = feat8[(size_t)s7 * 16 + l];
        acc8f8(a, v0); acc8f8(a, v1); acc8f8(a, v2); acc8f8(a, v3);
        acc8f8(a, v4); acc8f8(a, v5); acc8f8(a, v6); acc8f8(a, v7);
      }
      for (; e + 4 <= dd; e += 4) {
        int s0 = cs[e], s1 = cs[e + 1], s2 = cs[e + 2], s3 = cs[e + 3];
        uint2 v0 = feat8[(size_t)s0 * 16 + l];
        uint2 v1 = feat8[(size_t)s1 * 16 + l];
        uint2 v2 = feat8[(size_t)s2 * 16 + l];
        uint2 v3 = feat8[(size_t)s3 * 16 + l];
        acc8f8(a, v0); acc8f8(a, v1); acc8f8(a, v2); acc8f8(a, v3);
      }
      for (; e < dd; ++e) acc8f8(a, feat8[(size_t)cs[e] * 16 + l]);
      sc = 1.0f / fmaxf((float)dd, 1.0f);
    }
    uint4 o;
    o.x = (unsigned)f2b(a[0] * sc) | ((unsigned)f2b(a[1] * sc) << 16);
    o.y = (unsigned)f2b(a[2] * sc) | ((unsigned)f2b(a[3] * sc) << 16);
    o.z = (unsigned)f2b(a[4] * sc) | ((unsigned)f2b(a[5] * sc) << 16);
    o.w = (unsigned)f2b(a[6] * sc) | ((unsigned)f2b(a[7] * sc) << 16);
    *(uint4*)&hn[g][l * 8] = o;
  }
  __syncthreads();

  // ---- phase 2: GEMM ----
  int wave = tid >> 6, lane = tid & 63;
  int rg = wave >> 2;
  int cb0 = (wave & 3) * 2;
  int rowA = blockIdx.x * 64 + rg * 16 + (lane & 15);
  int kq = lane >> 4;
  bool valid = rowA < M;
  size_t abase = (size_t)rowA * DH + kq * 8;
  int lrow = rg * 16 + (lane & 15);
  f32x4 acc0 = {}, acc1 = {};
#pragma unroll
  for (int hf = 0; hf < 2; ++hf) {
#pragma unroll
    for (int ks = 0; ks < 4; ++ks) {
      bf16x8 a = {};
      if (hf == 0) {
        if (valid) a = __builtin_bit_cast(bf16x8, *(const uint4*)(feat + abase + ks * 32));
      } else {
        a = __builtin_bit_cast(bf16x8, *(const uint4*)&hn[lrow][ks * 32 + kq * 8]);
      }
      int sg = hf * 4 + ks;
      const ushort* wp = Wp + sg * 4096 + lane * 8;
      bf16x8 b0 = __builtin_bit_cast(bf16x8, *(const uint4*)(wp + cb0 * 512));
      bf16x8 b1 = __builtin_bit_cast(bf16x8, *(const uint4*)(wp + (cb0 + 1) * 512));
      acc0 = __builtin_amdgcn_mfma_f32_16x16x32_bf16(a, b0, acc0, 0, 0, 0);
      acc1 = __builtin_amdgcn_mfma_f32_16x16x32_bf16(a, b1, acc1, 0, 0, 0);
    }
  }
  // C/D layout: col = lane&15, row = (lane>>4)*4 + reg
  int col = lane & 15;
  int row0 = blockIdx.x * 64 + rg * 16 + (lane >> 4) * 4;
#pragma unroll
  for (int t = 0; t < 2; ++t) {
    int cb = cb0 + t;
    float bv = bias[cb * 16 + col];
    f32x4 acc = t ? acc1 : acc0;
#pragma unroll
    for (int j = 0; j < 4; ++j) {
      int rr = row0 + j;
      if (rr < M) {
        float v = acc[j] + bv;
        if (RELU) v = fmaxf(v, 0.f);
        if (OUTF32)
          ((float*)outp)[(size_t)rr * DH + cb * 16 + col] = v;
        else
          ((ushort*)outp)[(size_t)rr * DH + cb * 16 + col] = f2b(v);
        if (WRITEF8)
          outf8[(size_t)rr * DH + cb * 16 + col] = f2f8(v);
      }
    }
  }
}

extern "C" void kernel_launch(void* const* d_in, const int* in_sizes, int n_in,
                              void* d_out, int out_size, void* d_ws, size_t ws_size,
                              hipStream_t stream) {
  const float* x = (const float*)d_in[0];
  const int* src = (const int*)d_in[1];
  const int* dst = (const int*)d_in[2];
  const float* Wself1 = (const float*)d_in[3];
  const float* Wneigh1 = (const float*)d_in[4];
  const float* b1 = (const float*)d_in[5];
  const float* Wself2 = (const float*)d_in[6];
  const float* Wneigh2 = (const float*)d_in[7];
  const float* b2 = (const float*)d_in[8];
  int N = in_sizes[0] / DH;
  int E = in_sizes[1];

  char* w = (char*)d_ws;
  auto alloc = [&](size_t bytes) {
    char* p = w;
    w += (bytes + 255) & ~(size_t)255;
    return p;
  };
  ushort* xb = (ushort*)alloc((size_t)N * DH * 2);
  ushort* hb = (ushort*)alloc((size_t)N * DH * 2);
  unsigned char* xf8 = (unsigned char*)alloc((size_t)N * DH);
  unsigned char* hf8 = (unsigned char*)alloc((size_t)N * DH);
  ushort* Wp1 = (ushort*)alloc(32768 * 2);
  ushort* Wp2 = (ushort*)alloc(32768 * 2);
  int* deg = (int*)alloc((size_t)N * 4);
  int* colsrc = (int*)alloc((size_t)N * SLOTS * 4);

  // fused prep: zero deg | convert+fp8 | pack
  int nz4 = (N + 3) / 4;
  int nZero = (nz4 + 255) / 256;
  long n8 = (long)N * DH / 8;
  int nConv = (int)((n8 + 255) / 256);
  int nPack = (2 * 8 * 8 * 64 * 8 + 255) / 256;
  k_prep<<<nZero + nConv + nPack, 256, 0, stream>>>(
      (int4*)deg, nZero, nz4, x, xb, (uint2*)xf8, n8, nConv,
      Wself1, Wneigh1, Wself2, Wneigh2, Wp1, Wp2);

  // padded-CSR fill (vectorized scan)
  int nper = (N + 7) / 8;
  int nchunk = 256;
  int chunkSz = (((E + nchunk - 1) / nchunk) + 3) & ~3;  // multiple of 4
  k_fill8p<<<nchunk * 8, 256, 0, stream>>>(src, dst, deg, colsrc, E, nper, chunkSz);

  int gb = (N + 63) / 64;
  k_aggemm<1, 0, 1><<<gb, 1024, 0, stream>>>(xb, (const uint2*)xf8, deg, colsrc,
                                             Wp1, b1, hb, hf8, N);
  k_aggemm<0, 1, 0><<<gb, 1024, 0, stream>>>(hb, (const uint2*)hf8, deg, colsrc,
                                             Wp2, b2, d_out, nullptr, N);
}

// Round 16
// 127.660 us; speedup vs baseline: 1.3031x; 1.0233x over previous
//
#include <hip/hip_runtime.h>

#define DH 128
#define SLOTS 64
#define DPAD 16  // deg stride: one counter per 64B line (atomic contention fix)

typedef __bf16 bf16x8 __attribute__((ext_vector_type(8)));
typedef float f32x4 __attribute__((ext_vector_type(4)));
typedef float f32x2 __attribute__((ext_vector_type(2)));

__device__ __forceinline__ ushort f2b(float f) {
  union { float f; unsigned u; } c; c.f = f;
  unsigned u = c.u;
  unsigned r = (u + 0x7fffu + ((u >> 16) & 1u)) >> 16;
  return (ushort)r;
}
__device__ __forceinline__ unsigned char f2f8(float v) {
  return (unsigned char)(__builtin_amdgcn_cvt_pk_fp8_f32(v, v, 0, false) & 0xff);
}

// ---- fused: zero deg | convert f32 -> bf16 + fp8 | weight pack ----
__global__ void k_prep(int4* __restrict__ degz, int nZero, int nz4,
                       const float* __restrict__ x, ushort* __restrict__ xb,
                       uint2* __restrict__ xf8, long n8, int nConv,
                       const float* __restrict__ Ws1, const float* __restrict__ Wn1,
                       const float* __restrict__ Ws2, const float* __restrict__ Wn2,
                       ushort* __restrict__ Wp1, ushort* __restrict__ Wp2) {
  int bid = blockIdx.x;
  if (bid < nZero) {
    int i = bid * 256 + threadIdx.x;
    if (i < nz4) degz[i] = int4{0, 0, 0, 0};
  } else if (bid < nZero + nConv) {
    long i = (long)(bid - nZero) * 256 + threadIdx.x;
    if (i >= n8) return;
    const float4* p = (const float4*)x + i * 2;
    float4 a = p[0], b = p[1];
    uint4 o;
    o.x = (unsigned)f2b(a.x) | ((unsigned)f2b(a.y) << 16);
    o.y = (unsigned)f2b(a.z) | ((unsigned)f2b(a.w) << 16);
    o.z = (unsigned)f2b(b.x) | ((unsigned)f2b(b.y) << 16);
    o.w = (unsigned)f2b(b.z) | ((unsigned)f2b(b.w) << 16);
    ((uint4*)xb)[i] = o;
    int w0 = __builtin_amdgcn_cvt_pk_fp8_f32(a.x, a.y, 0, false);
    w0 = __builtin_amdgcn_cvt_pk_fp8_f32(a.z, a.w, w0, true);
    int w1 = __builtin_amdgcn_cvt_pk_fp8_f32(b.x, b.y, 0, false);
    w1 = __builtin_amdgcn_cvt_pk_fp8_f32(b.z, b.w, w1, true);
    xf8[i] = uint2{(unsigned)w0, (unsigned)w1};
  } else {
    int idx = (bid - nZero - nConv) * 256 + threadIdx.x;
    if (idx >= 2 * 8 * 8 * 64 * 8) return;
    int layer = idx >> 15;
    int t = idx & 32767;
    int j = t & 7;
    int lane = (t >> 3) & 63;
    int cb = (t >> 9) & 7;
    int s = (t >> 12) & 7;
    int col = cb * 16 + (lane & 15);
    int k = s * 32 + ((lane >> 4) * 8) + j;
    const float* Wself = layer ? Ws2 : Ws1;
    const float* Wneigh = layer ? Wn2 : Wn1;
    float v = (k < 128) ? Wself[k * 128 + col] : Wneigh[(k - 128) * 128 + col];
    (layer ? Wp2 : Wp1)[t] = f2b(v);
  }
}

// ---- padded-CSR fill, XCD-partitioned by dst range ----
// deg padded to 1 counter / 64B line: line-level atomic serialization drops 16x.
__global__ void k_fill8p(const int* __restrict__ src, const int* __restrict__ dst,
                         int* __restrict__ deg, int* __restrict__ colsrc,
                         int E, int nper, int chunkSz) {
  int part = blockIdx.x & 7;
  int chunk = blockIdx.x >> 3;
  int lo = part * nper, hi = lo + nper;
  int base = chunk * chunkSz;  // chunkSz % 4 == 0
  int end = min(base + chunkSz, E);
  int i = base + threadIdx.x * 4;
  for (; i + 4 <= end; i += 1024) {
    int4 d4 = *(const int4*)(dst + i);
    int dd[4] = {d4.x, d4.y, d4.z, d4.w};
#pragma unroll
    for (int k = 0; k < 4; ++k) {
      int d = dd[k];
      if (d >= lo && d < hi) {
        int s = src[i + k];
        int r = atomicAdd(&deg[(size_t)d * DPAD], 1);
        if (r < SLOTS) colsrc[(size_t)d * SLOTS + r] = s;
      }
    }
  }
  for (; i < end; ++i) {
    int d = dst[i];
    if (d >= lo && d < hi) {
      int s = src[i];
      int r = atomicAdd(&deg[(size_t)d * DPAD], 1);
      if (r < SLOTS) colsrc[(size_t)d * SLOTS + r] = s;
    }
  }
}

// decode 8 fp8 (e4m3) from uint2 and accumulate
__device__ __forceinline__ void acc8f8(float* a, uint2 v) {
  f32x2 p0 = __builtin_amdgcn_cvt_pk_f32_fp8(v.x, false);
  f32x2 p1 = __builtin_amdgcn_cvt_pk_f32_fp8(v.x, true);
  f32x2 p2 = __builtin_amdgcn_cvt_pk_f32_fp8(v.y, false);
  f32x2 p3 = __builtin_amdgcn_cvt_pk_f32_fp8(v.y, true);
  a[0] += p0.x; a[1] += p0.y; a[2] += p1.x; a[3] += p1.y;
  a[4] += p2.x; a[5] += p2.y; a[6] += p3.x; a[7] += p3.y;
}

// ---- fused aggregate + GEMM, 1024 threads / 64 nodes per block (R12 core) ----
template <int RELU, int OUTF32, int WRITEF8>
__global__ __launch_bounds__(1024, 8) void k_aggemm(
    const ushort* __restrict__ feat, const uint2* __restrict__ feat8,
    const int* __restrict__ deg, const int* __restrict__ colsrc,
    const ushort* __restrict__ Wp, const float* __restrict__ bias,
    void* __restrict__ outp, unsigned char* __restrict__ outf8, int M) {
  __shared__ ushort hn[64][136];
  int tid = threadIdx.x;

  // ---- phase 1: aggregation (fp8 gathers over padded CSR) ----
  {
    int g = tid >> 4, l = tid & 15;
    int node = blockIdx.x * 64 + g;
    float a[8] = {0.f, 0.f, 0.f, 0.f, 0.f, 0.f, 0.f, 0.f};
    float sc = 0.f;
    if (node < M) {
      int dd = min(deg[(size_t)node * DPAD], SLOTS);
      const int* cs = colsrc + (size_t)node * SLOTS;
      int e = 0;
      for (; e + 8 <= dd; e += 8) {
        int s0 = cs[e], s1 = cs[e + 1], s2 = cs[e + 2], s3 = cs[e + 3];
        int s4 = cs[e + 4], s5 = cs[e + 5], s6 = cs[e + 6], s7 = cs[e + 7];
        uint2 v0 = feat8[(size_t)s0 * 16 + l];
        uint2 v1 = feat8[(size_t)s1 * 16 + l];
        uint2 v2 = feat8[(size_t)s2 * 16 + l];
        uint2 v3 = feat8[(size_t)s3 * 16 + l];
        uint2 v4 = feat8[(size_t)s4 * 16 + l];
        uint2 v5 = feat8[(size_t)s5 * 16 + l];
        uint2 v6 = feat8[(size_t)s6 * 16 + l];
        uint2 v7 = feat8[(size_t)s7 * 16 + l];
        acc8f8(a, v0); acc8f8(a, v1); acc8f8(a, v2); acc8f8(a, v3);
        acc8f8(a, v4); acc8f8(a, v5); acc8f8(a, v6); acc8f8(a, v7);
      }
      for (; e + 4 <= dd; e += 4) {
        int s0 = cs[e], s1 = cs[e + 1], s2 = cs[e + 2], s3 = cs[e + 3];
        uint2 v0 = feat8[(size_t)s0 * 16 + l];
        uint2 v1 = feat8[(size_t)s1 * 16 + l];
        uint2 v2 = feat8[(size_t)s2 * 16 + l];
        uint2 v3 = feat8[(size_t)s3 * 16 + l];
        acc8f8(a, v0); acc8f8(a, v1); acc8f8(a, v2); acc8f8(a, v3);
      }
      for (; e < dd; ++e) acc8f8(a, feat8[(size_t)cs[e] * 16 + l]);
      sc = 1.0f / fmaxf((float)dd, 1.0f);
    }
    uint4 o;
    o.x = (unsigned)f2b(a[0] * sc) | ((unsigned)f2b(a[1] * sc) << 16);
    o.y = (unsigned)f2b(a[2] * sc) | ((unsigned)f2b(a[3] * sc) << 16);
    o.z = (unsigned)f2b(a[4] * sc) | ((unsigned)f2b(a[5] * sc) << 16);
    o.w = (unsigned)f2b(a[6] * sc) | ((unsigned)f2b(a[7] * sc) << 16);
    *(uint4*)&hn[g][l * 8] = o;
  }
  __syncthreads();

  // ---- phase 2: GEMM ----
  int wave = tid >> 6, lane = tid & 63;
  int rg = wave >> 2;
  int cb0 = (wave & 3) * 2;
  int rowA = blockIdx.x * 64 + rg * 16 + (lane & 15);
  int kq = lane >> 4;
  bool valid = rowA < M;
  size_t abase = (size_t)rowA * DH + kq * 8;
  int lrow = rg * 16 + (lane & 15);
  f32x4 acc0 = {}, acc1 = {};
#pragma unroll
  for (int hf = 0; hf < 2; ++hf) {
#pragma unroll
    for (int ks = 0; ks < 4; ++ks) {
      bf16x8 a = {};
      if (hf == 0) {
        if (valid) a = __builtin_bit_cast(bf16x8, *(const uint4*)(feat + abase + ks * 32));
      } else {
        a = __builtin_bit_cast(bf16x8, *(const uint4*)&hn[lrow][ks * 32 + kq * 8]);
      }
      int sg = hf * 4 + ks;
      const ushort* wp = Wp + sg * 4096 + lane * 8;
      bf16x8 b0 = __builtin_bit_cast(bf16x8, *(const uint4*)(wp + cb0 * 512));
      bf16x8 b1 = __builtin_bit_cast(bf16x8, *(const uint4*)(wp + (cb0 + 1) * 512));
      acc0 = __builtin_amdgcn_mfma_f32_16x16x32_bf16(a, b0, acc0, 0, 0, 0);
      acc1 = __builtin_amdgcn_mfma_f32_16x16x32_bf16(a, b1, acc1, 0, 0, 0);
    }
  }
  // C/D layout: col = lane&15, row = (lane>>4)*4 + reg
  int col = lane & 15;
  int row0 = blockIdx.x * 64 + rg * 16 + (lane >> 4) * 4;
#pragma unroll
  for (int t = 0; t < 2; ++t) {
    int cb = cb0 + t;
    float bv = bias[cb * 16 + col];
    f32x4 acc = t ? acc1 : acc0;
#pragma unroll
    for (int j = 0; j < 4; ++j) {
      int rr = row0 + j;
      if (rr < M) {
        float v = acc[j] + bv;
        if (RELU) v = fmaxf(v, 0.f);
        if (OUTF32)
          ((float*)outp)[(size_t)rr * DH + cb * 16 + col] = v;
        else
          ((ushort*)outp)[(size_t)rr * DH + cb * 16 + col] = f2b(v);
        if (WRITEF8)
          outf8[(size_t)rr * DH + cb * 16 + col] = f2f8(v);
      }
    }
  }
}

extern "C" void kernel_launch(void* const* d_in, const int* in_sizes, int n_in,
                              void* d_out, int out_size, void* d_ws, size_t ws_size,
                              hipStream_t stream) {
  const float* x = (const float*)d_in[0];
  const int* src = (const int*)d_in[1];
  const int* dst = (const int*)d_in[2];
  const float* Wself1 = (const float*)d_in[3];
  const float* Wneigh1 = (const float*)d_in[4];
  const float* b1 = (const float*)d_in[5];
  const float* Wself2 = (const float*)d_in[6];
  const float* Wneigh2 = (const float*)d_in[7];
  const float* b2 = (const float*)d_in[8];
  int N = in_sizes[0] / DH;
  int E = in_sizes[1];

  char* w = (char*)d_ws;
  auto alloc = [&](size_t bytes) {
    char* p = w;
    w += (bytes + 255) & ~(size_t)255;
    return p;
  };
  ushort* xb = (ushort*)alloc((size_t)N * DH * 2);
  ushort* hb = (ushort*)alloc((size_t)N * DH * 2);
  unsigned char* xf8 = (unsigned char*)alloc((size_t)N * DH);
  unsigned char* hf8 = (unsigned char*)alloc((size_t)N * DH);
  ushort* Wp1 = (ushort*)alloc(32768 * 2);
  ushort* Wp2 = (ushort*)alloc(32768 * 2);
  int* deg = (int*)alloc((size_t)N * DPAD * 4);
  int* colsrc = (int*)alloc((size_t)N * SLOTS * 4);

  // fused prep: zero deg (3.2MB padded) | convert+fp8 | pack
  int nz4 = (N * DPAD + 3) / 4;
  int nZero = (nz4 + 255) / 256;
  long n8 = (long)N * DH / 8;
  int nConv = (int)((n8 + 255) / 256);
  int nPack = (2 * 8 * 8 * 64 * 8 + 255) / 256;
  k_prep<<<nZero + nConv + nPack, 256, 0, stream>>>(
      (int4*)deg, nZero, nz4, x, xb, (uint2*)xf8, n8, nConv,
      Wself1, Wneigh1, Wself2, Wneigh2, Wp1, Wp2);

  // padded-CSR fill (padded deg counters)
  int nper = (N + 7) / 8;
  int nchunk = 256;
  int chunkSz = (((E + nchunk - 1) / nchunk) + 3) & ~3;  // multiple of 4
  k_fill8p<<<nchunk * 8, 256, 0, stream>>>(src, dst, deg, colsrc, E, nper, chunkSz);

  int gb = (N + 63) / 64;
  k_aggemm<1, 0, 1><<<gb, 1024, 0, stream>>>(xb, (const uint2*)xf8, deg, colsrc,
                                             Wp1, b1, hb, hf8, N);
  k_aggemm<0, 1, 0><<<gb, 1024, 0, stream>>>(hb, (const uint2*)hf8, deg, colsrc,
                                             Wp2, b2, d_out, nullptr, N);
}